// Round 12
// baseline (465.435 us; speedup 1.0000x reference)
//
#include <hip/hip_runtime.h>

// RVQ: z [16,64,4096] f32, codebooks [8,1024,64] f32 -> zq + 8 losses + 8 perplexities
#define S      8
#define K      1024
#define D      64
#define NVEC   65536
#define NW     1024      // single-wave blocks, 64 vectors each (quad row-set)
#define NELEM  4194304.0f
#define EPSQ   1e-10f
#define DELTA  0.005f    // exact-rescan margin >> split-bf16 score error (~2e-3 worst)

typedef __attribute__((ext_vector_type(8))) short  short8;   // 8 bf16
typedef __attribute__((ext_vector_type(4))) float  float4v;  // MFMA acc

static __device__ inline unsigned short f2bf(float f) {
    unsigned int u = __float_as_uint(f);
    u = (u + 0x7FFFu + ((u >> 16) & 1u)) >> 16;
    return (unsigned short)u;
}
static __device__ inline float bf2f(unsigned short h) {
    return __uint_as_float(((unsigned int)h) << 16);
}

// ---------------------------------------------------------------------------
// Prep: (a) c2 + zero cnt; (b) interleave codebook into B-fragment streaming
// records, PRE-SCALED BY -2 so the MFMA accumulates -2*dot directly and the
// accumulator is seeded with c2 (score = acc, no per-score fmaf).
// Record = 4KB per (stage, 16-cw tile): segments at byte 0/1024/2048/3072
// ([h0h][h1h][h0l][h1l]), each segment 64 lanes x 16B.
// ---------------------------------------------------------------------------
__global__ void rvq_prep(const float* __restrict__ cb,
                         unsigned short* __restrict__ cbi,
                         float* __restrict__ c2, unsigned* __restrict__ cnt) {
    int i = blockIdx.x * blockDim.x + threadIdx.x;   // 0..32767
    if (i < S * K) {   // c2 + cnt zero
        const float* row = cb + (size_t)i * D;
        float a0 = 0.f, a1 = 0.f, a2 = 0.f, a3 = 0.f;
#pragma unroll
        for (int d = 0; d < D; d += 4) {
            a0 = fmaf(row[d+0], row[d+0], a0);
            a1 = fmaf(row[d+1], row[d+1], a1);
            a2 = fmaf(row[d+2], row[d+2], a2);
            a3 = fmaf(row[d+3], row[d+3], a3);
        }
        c2[i] = (a0 + a1) + (a2 + a3);
        cnt[i] = 0u;
    }
    // interleave: i = s*4096 + tau*64 + l
    int s  = i >> 12;
    int tau = (i >> 6) & 63;
    int l  = i & 63;
    int m  = l & 15, qq = l >> 4;
    const float* row = cb + (size_t)(s * K + tau * 16 + m) * D;
    short8 h0h, h0l, h1h, h1l;
#pragma unroll
    for (int e = 0; e < 8; ++e) {
        float x = -2.0f * row[qq * 8 + e];
        unsigned short h = f2bf(x);
        h0h[e] = (short)h; h0l[e] = (short)f2bf(x - bf2f(h));
        float y = -2.0f * row[32 + qq * 8 + e];
        unsigned short g = f2bf(y);
        h1h[e] = (short)g; h1l[e] = (short)f2bf(y - bf2f(g));
    }
    unsigned short* rec = cbi + (size_t)(s * 64 + tau) * 2048 + l * 8;
    *(short8*)(rec +    0) = h0h;
    *(short8*)(rec +  512) = h1h;
    *(short8*)(rec + 1024) = h0l;
    *(short8*)(rec + 1536) = h1l;
}

// ---------------------------------------------------------------------------
// Main (R12): QUAD row-set. R11 falsified the occupancy lever (2x waves,
// occupancy counter unchanged, time +12%); the only lever that has moved
// the wall (R10, -20%) is per-MFMA amortization + independent in-wave MFMA
// chains. Push it: 1024 single-wave blocks x 64 vectors; per 4KB tile
// 24 MFMA as EIGHT independent 3-chains sharing 5 loads (loads/MFMA halved
// vs R10, chain-dependent MFMAs 8 issue slots apart -> MFMA latency covered
// in-wave, so 1 wave/SIMD residency is fine). Residuals LDS-resident
// (rsp[64][65], 16.6KB). Tail phases = mechanical 4-set R10.
//
// launch_bounds EMPIRICAL RULE (R0-R4,R11): VGPR cap = 256/arg2 on this
// toolchain. Quad-set needs ~210 VGPR -> arg2 MUST be 1 (cap 256).
// Expected VGPR ~200-215; spill signature = FETCH explosion -> revert R10.
// ---------------------------------------------------------------------------
__global__ __launch_bounds__(64, 1)
void rvq_main(const float* __restrict__ z, const float* __restrict__ cbf,
              const unsigned short* __restrict__ cbi,
              const float* __restrict__ c2, float* __restrict__ zq,
              float* __restrict__ lossp, unsigned* __restrict__ cnt) {
    const int lane = threadIdx.x;
    const int m    = lane & 15;
    const int q    = lane >> 4;
    const int wid  = blockIdx.x;
    const int vbase = wid * 64;
    const int b    = vbase >> 12;
    const int ta   = (vbase & 4095) + m;    // rows  0..15
    const int tb   = ta + 16;               // rows 16..31
    const int tc   = ta + 32;               // rows 32..47
    const int td   = ta + 48;               // rows 48..63
    const size_t zrow = ((size_t)(b * 64)) << 12;
    const int lo16 = lane * 16;     // per-lane byte offset into a segment
    const int lom  = m * 4;         // per-lane byte offset into c2 tile

    __shared__ float rsp[64][65];   // residual spill, +1 pad (16.6 KB)

    // ---- init: residuals <- z ----
#pragma unroll
    for (int i = 0; i < 8; ++i) {
        rsp[m][q*8+i]       = z[zrow + ((size_t)(q*8+i)    << 12) + ta];
        rsp[m][32+q*8+i]    = z[zrow + ((size_t)(32+q*8+i) << 12) + ta];
        rsp[16+m][q*8+i]    = z[zrow + ((size_t)(q*8+i)    << 12) + tb];
        rsp[16+m][32+q*8+i] = z[zrow + ((size_t)(32+q*8+i) << 12) + tb];
        rsp[32+m][q*8+i]    = z[zrow + ((size_t)(q*8+i)    << 12) + tc];
        rsp[32+m][32+q*8+i] = z[zrow + ((size_t)(32+q*8+i) << 12) + tc];
        rsp[48+m][q*8+i]    = z[zrow + ((size_t)(q*8+i)    << 12) + td];
        rsp[48+m][32+q*8+i] = z[zrow + ((size_t)(32+q*8+i) << 12) + td];
    }

// load one 4KB tile record + its c2 scalar; advance uniform bases (SALU)
#define LOADB(i) {                                                           \
        B##i##0 = *(const short8*)(tp + lo16);                               \
        B##i##1 = *(const short8*)(tp + lo16 + 1024);                        \
        B##i##2 = *(const short8*)(tp + lo16 + 2048);                        \
        B##i##3 = *(const short8*)(tp + lo16 + 3072);                        \
        cc##i   = *(const float*)(cp + lom);                                 \
        tp += 4096; cp += 64;                                                \
    }

#define MF(A,B,C) __builtin_amdgcn_mfma_f32_16x16x32_bf16(A,B,C,0,0,0)

// top-2 score update for one set, 4 outputs
#define SCUP(p0, p1, b1X, b2X, k1X) {                                        \
        _Pragma("unroll")                                                    \
        for (int j = 0; j < 4; ++j) {                                        \
            float sx = p0[j] + p1[j];                                        \
            b2X[j] = __builtin_amdgcn_fmed3f(sx, b1X[j], b2X[j]);            \
            k1X[j] = (sx < b1X[j]) ? ncol : k1X[j];                          \
            b1X[j] = fminf(sx, b1X[j]);                                      \
        }                                                                    \
    }

// 24 MFMA as 8 independent 3-chains (4 sets x dims 0-31 / 32-63)
#define COMPUTE(i, tt) {                                                     \
        float4v pa0 = {cc##i, cc##i, cc##i, cc##i}, pa1 = {0.f,0.f,0.f,0.f}; \
        float4v pb0 = {cc##i, cc##i, cc##i, cc##i}, pb1 = {0.f,0.f,0.f,0.f}; \
        float4v pc0 = {cc##i, cc##i, cc##i, cc##i}, pc1 = {0.f,0.f,0.f,0.f}; \
        float4v pd0 = {cc##i, cc##i, cc##i, cc##i}, pd1 = {0.f,0.f,0.f,0.f}; \
        __builtin_amdgcn_s_setprio(1);                                       \
        pa0 = MF(xa0h, B##i##0, pa0); pb0 = MF(xb0h, B##i##0, pb0);          \
        pc0 = MF(xc0h, B##i##0, pc0); pd0 = MF(xd0h, B##i##0, pd0);          \
        pa1 = MF(xa1h, B##i##1, pa1); pb1 = MF(xb1h, B##i##1, pb1);          \
        pc1 = MF(xc1h, B##i##1, pc1); pd1 = MF(xd1h, B##i##1, pd1);          \
        pa0 = MF(xa0l, B##i##0, pa0); pb0 = MF(xb0l, B##i##0, pb0);          \
        pc0 = MF(xc0l, B##i##0, pc0); pd0 = MF(xd0l, B##i##0, pd0);          \
        pa1 = MF(xa1l, B##i##1, pa1); pb1 = MF(xb1l, B##i##1, pb1);          \
        pc1 = MF(xc1l, B##i##1, pc1); pd1 = MF(xd1l, B##i##1, pd1);          \
        pa0 = MF(xa0h, B##i##2, pa0); pb0 = MF(xb0h, B##i##2, pb0);          \
        pc0 = MF(xc0h, B##i##2, pc0); pd0 = MF(xd0h, B##i##2, pd0);          \
        pa1 = MF(xa1h, B##i##3, pa1); pb1 = MF(xb1h, B##i##3, pb1);          \
        pc1 = MF(xc1h, B##i##3, pc1); pd1 = MF(xd1h, B##i##3, pd1);          \
        __builtin_amdgcn_s_setprio(0);                                       \
        const int ncol = (tt) * 16 + m;                                      \
        SCUP(pa0, pa1, b1a, b2a, k1a)                                        \
        SCUP(pb0, pb1, b1b, b2b, k1b)                                        \
        SCUP(pc0, pc1, b1c, b2c, k1c)                                        \
        SCUP(pd0, pd1, b1d, b2d, k1d)                                        \
    }

// split one LDS residual row-pair into hi/lo frags
#define REBUILD(row, xh0, xl0, xh1, xl1) {                                   \
        _Pragma("unroll")                                                    \
        for (int i = 0; i < 8; ++i) {                                        \
            unsigned short h; float v;                                       \
            v = rsp[row][q*8+i];    h = f2bf(v);                             \
            xh0[i] = (short)h; xl0[i] = (short)f2bf(v - bf2f(h));            \
            v = rsp[row][32+q*8+i]; h = f2bf(v);                             \
            xh1[i] = (short)h; xl1[i] = (short)f2bf(v - bf2f(h));            \
        }                                                                    \
    }

#pragma unroll 1
    for (int s = 0; s < S; ++s) {
        short8 xa0h, xa0l, xa1h, xa1l, xb0h, xb0l, xb1h, xb1l;
        short8 xc0h, xc0l, xc1h, xc1l, xd0h, xd0l, xd1h, xd1l;
        REBUILD(m,      xa0h, xa0l, xa1h, xa1l)
        REBUILD(16 + m, xb0h, xb0l, xb1h, xb1l)
        REBUILD(32 + m, xc0h, xc0l, xc1h, xc1l)
        REBUILD(48 + m, xd0h, xd0l, xd1h, xd1l)

        float b1a[4], b2a[4], b1b[4], b2b[4];
        float b1c[4], b2c[4], b1d[4], b2d[4];
        int   k1a[4], k1b[4], k1c[4], k1d[4];
#pragma unroll
        for (int j = 0; j < 4; ++j) {
            b1a[j] = 3.4e38f; b2a[j] = 3.4e38f; k1a[j] = 0;
            b1b[j] = 3.4e38f; b2b[j] = 3.4e38f; k1b[j] = 0;
            b1c[j] = 3.4e38f; b2c[j] = 3.4e38f; k1c[j] = 0;
            b1d[j] = 3.4e38f; b2d[j] = 3.4e38f; k1d[j] = 0;
        }

        const float* c2s = c2 + s * K;
        const char*  tp  = (const char*)(cbi + (size_t)s * 131072); // uniform
        const char*  cp  = (const char*)c2s;                        // uniform

        short8 B00, B01, B02, B03, B10, B11, B12, B13;  // two banks
        float  cc0, cc1;

        LOADB(0) LOADB(1)

#pragma unroll 1
        for (int it = 0; it < 31; ++it) {
            const int tau = it * 2;
            COMPUTE(0, tau + 0) LOADB(0)     // reload tile tau+2
            COMPUTE(1, tau + 1) LOADB(1)     // reload tile tau+3
        }
        COMPUTE(0, 62) COMPUTE(1, 63)

        // ---- reduce across the 16 col-lanes (k-tie: lowest k) ----
#define RED(b1X, b2X, k1X) {                                                 \
        _Pragma("unroll")                                                    \
        for (int off = 1; off < 16; off <<= 1) {                             \
            _Pragma("unroll")                                                \
            for (int j = 0; j < 4; ++j) {                                    \
                float o1 = __shfl_xor(b1X[j], off);                          \
                int   ok = __shfl_xor(k1X[j], off);                          \
                float o2 = __shfl_xor(b2X[j], off);                          \
                float n2 = fminf(fminf(b2X[j], o2), fmaxf(b1X[j], o1));      \
                bool tk = (o1 < b1X[j]) || (o1 == b1X[j] && ok < k1X[j]);    \
                k1X[j] = tk ? ok : k1X[j];                                   \
                b1X[j] = fminf(b1X[j], o1); b2X[j] = n2;                     \
            }                                                                \
        }                                                                    \
    }
        RED(b1a, b2a, k1a) RED(b1b, b2b, k1b)
        RED(b1c, b2c, k1c) RED(b1d, b2d, k1d)
#undef RED

        // ---- δ-rescue: exact fp32 rescan of ambiguous rows (rare) ----
        const float* cr0 = cbf + (size_t)s * 65536;
#define RESCUE(b1X, b2X, k1X, ROW)                                            \
        for (int j = 0; j < 4; ++j) {                                         \
            unsigned long long mask = __ballot(b2X[j] - b1X[j] < DELTA);      \
            while (mask) {                                                    \
                int lq = (int)(__builtin_ctzll(mask)) >> 4;                   \
                mask &= ~(0xFFFFULL << (lq * 16));                            \
                int mrow = lq * 4 + j;                                        \
                float bd = 3.4e38f; int bk = 0;                               \
                for (int cc = 0; cc < 16; ++cc) {                             \
                    int n = cc * 64 + lane;                                   \
                    const float* crow = cr0 + (size_t)n * 64;                 \
                    float dot = 0.f;                                          \
                    for (int d = 0; d < 64; ++d)                              \
                        dot = fmaf(rsp[(ROW) + mrow][d], crow[d], dot);       \
                    float sc = c2s[n] - 2.f * dot;                            \
                    if (sc < bd) { bd = sc; bk = n; }                         \
                }                                                             \
                for (int off = 1; off < 64; off <<= 1) {                      \
                    float ob = __shfl_xor(bd, off); int ok = __shfl_xor(bk, off); \
                    bool tk = (ob < bd) || (ob == bd && ok < bk);             \
                    bk = tk ? ok : bk; bd = fminf(bd, ob);                    \
                }                                                             \
                if (q == lq) k1X[j] = bk;                                     \
            }                                                                 \
        }
        RESCUE(b1a, b2a, k1a, 0)
        RESCUE(b1b, b2b, k1b, 16)
        RESCUE(b1c, b2c, k1c, 32)
        RESCUE(b1d, b2d, k1d, 48)
#undef RESCUE

        // ---- transpose winners, update rsp, loss, hist (per set) ----
        int mm = m & 3, src = (m >> 2) * 16;
        float ls = 0.f;
#define FINISH(k1X, ROW) {                                                   \
        int w0 = __shfl(k1X[0], src), w1 = __shfl(k1X[1], src);              \
        int w2 = __shfl(k1X[2], src), w3 = __shfl(k1X[3], src);              \
        int bk = (mm == 0) ? w0 : (mm == 1) ? w1 : (mm == 2) ? w2 : w3;      \
        const float* qv = cbf + (size_t)s * 65536 + (size_t)bk * 64;         \
        _Pragma("unroll")                                                    \
        for (int i = 0; i < 8; ++i) {                                        \
            float n0 = rsp[(ROW)+m][q*8+i]    - qv[q*8+i];                   \
            float n1 = rsp[(ROW)+m][32+q*8+i] - qv[32+q*8+i];                \
            rsp[(ROW)+m][q*8+i] = n0;  rsp[(ROW)+m][32+q*8+i] = n1;          \
            ls = fmaf(n0, n0, ls); ls = fmaf(n1, n1, ls);                    \
        }                                                                    \
        if (q == 0) atomicAdd(&cnt[s * K + bk], 1u);                         \
    }
        FINISH(k1a, 0)
        FINISH(k1b, 16)
        FINISH(k1c, 32)
        FINISH(k1d, 48)
#undef FINISH
#pragma unroll
        for (int off = 1; off < 64; off <<= 1) ls += __shfl_xor(ls, off);
        if (lane == 0) lossp[s * NW + wid] = ls;
    }
#undef LOADB
#undef COMPUTE
#undef SCUP
#undef REBUILD

    // ---- epilogue: zq = z - r_final ----
#pragma unroll
    for (int i = 0; i < 8; ++i) {
        size_t a0 = zrow + ((size_t)(q*8+i)    << 12);
        size_t a1 = zrow + ((size_t)(32+q*8+i) << 12);
        zq[a0 + ta] = z[a0 + ta] - rsp[m][q*8+i];
        zq[a1 + ta] = z[a1 + ta] - rsp[m][32+q*8+i];
        zq[a0 + tb] = z[a0 + tb] - rsp[16+m][q*8+i];
        zq[a1 + tb] = z[a1 + tb] - rsp[16+m][32+q*8+i];
        zq[a0 + tc] = z[a0 + tc] - rsp[32+m][q*8+i];
        zq[a1 + tc] = z[a1 + tc] - rsp[32+m][32+q*8+i];
        zq[a0 + td] = z[a0 + td] - rsp[48+m][q*8+i];
        zq[a1 + td] = z[a1 + td] - rsp[48+m][32+q*8+i];
    }
}

// ---------------------------------------------------------------------------
// Finalize: losses (mean of summed wave partials) + perplexities
// ---------------------------------------------------------------------------
__global__ void rvq_finalize(const float* __restrict__ lossp,
                             const unsigned* __restrict__ cnt,
                             float* __restrict__ out_loss,
                             float* __restrict__ out_perp) {
    const int s   = blockIdx.x;
    const int tid = threadIdx.x;
    float ent = 0.f, lsum = 0.f;
    for (int i = tid; i < K; i += 256) {
        float p = (float)cnt[s * K + i] * (1.0f / 65536.0f);
        ent += p * logf(p + EPSQ);
    }
    for (int i = tid; i < NW; i += 256) lsum += lossp[s * NW + i];
    __shared__ float redE[4], redL[4];
#pragma unroll
    for (int off = 32; off > 0; off >>= 1) {
        ent  += __shfl_down(ent, off);
        lsum += __shfl_down(lsum, off);
    }
    if ((tid & 63) == 0) { redE[tid >> 6] = ent; redL[tid >> 6] = lsum; }
    __syncthreads();
    if (tid == 0) {
        float te = redE[0] + redE[1] + redE[2] + redE[3];
        float tl = redL[0] + redL[1] + redL[2] + redL[3];
        out_perp[s] = expf(-te);
        out_loss[s] = tl * (1.0f / NELEM);
    }
}

// ---------------------------------------------------------------------------
extern "C" void kernel_launch(void* const* d_in, const int* in_sizes, int n_in,
                              void* d_out, int out_size, void* d_ws, size_t ws_size,
                              hipStream_t stream) {
    const float* z  = (const float*)d_in[0];
    const float* cb = (const float*)d_in[1];

    float* zq       = (float*)d_out;
    float* out_loss = zq + 4194304;
    float* out_perp = out_loss + 8;

    // ws: cbi 2 MB | c2 32 KB | cnt 32 KB | lossp 32 KB
    char* ws = (char*)d_ws;
    unsigned short* cbi = (unsigned short*)(ws);
    float*    c2    = (float*)(ws + 2097152);
    unsigned* cnt   = (unsigned*)(ws + 2129920);
    float*    lossp = (float*)(ws + 2162688);

    hipLaunchKernelGGL(rvq_prep,     dim3(128),  dim3(256), 0, stream, cb, cbi, c2, cnt);
    hipLaunchKernelGGL(rvq_main,     dim3(NW),   dim3(64),  0, stream, z, cb, cbi, c2, zq, lossp, cnt);
    hipLaunchKernelGGL(rvq_finalize, dim3(S),    dim3(256), 0, stream, lossp, cnt, out_loss, out_perp);
}